// Round 1
// baseline (1864.871 us; speedup 1.0000x reference)
//
#include <hip/hip_runtime.h>

#define ROWS   681408        // 64 * 10647
#define NBINS  8192
#define TOPK   512
#define SELCAP 1024

// ws word offsets
#define WS_COUNT    0
#define WS_SELCOUNT 1
#define WS_BSTAR    2
#define WS_ROW0     4        // 6 floats: score, class, x1,y1,x2,y2
#define WS_HIST     16       // 8192 uints
#define WS_SEL      8448     // uint2[SELCAP] -> words 8448..10495
#define WS_CAND     10496    // uint2[candCap]

__device__ __forceinline__ float clip01(float v) {
    return fminf(fmaxf(v, 0.0f), 1.0f);
}

__global__ void init_kernel(unsigned int* __restrict__ ws) {
    int i = blockIdx.x * 256 + threadIdx.x;
    if (i < NBINS) ws[WS_HIST + i] = 0u;
    if (i < 3) ws[i] = 0u;
}

__global__ __launch_bounds__(256) void decode_kernel(
    const float* __restrict__ y, unsigned int* __restrict__ ws,
    uint2* __restrict__ cand, int candCap)
{
    const int t    = threadIdx.x;
    const int lane = t & 63;
    const int wave = t >> 6;
    const int g    = lane >> 4;   // 16-lane group within wave
    const int s    = lane & 15;
    const int row  = blockIdx.x * 16 + wave * 4 + g;   // exact grid, no tail

    const float* p = y + (size_t)row * 85;
    float e0 = p[s];
    float e1 = p[s + 16];
    float e2 = p[s + 32];
    float e3 = p[s + 48];
    float e4 = p[s + 64];
    float e5 = (s < 5) ? p[s + 80] : -1.0f;

    // per-lane argmax over probs (elements 5..84), fold in ascending class
    // order with strict > so the FIRST index wins ties (jnp.argmax semantics)
    float bv; int bc;
    if (s >= 5) { bv = e0; bc = s - 5; } else { bv = -1.0f; bc = 1 << 20; }
    if (e1 > bv) { bv = e1; bc = s + 11; }
    if (e2 > bv) { bv = e2; bc = s + 27; }
    if (e3 > bv) { bv = e3; bc = s + 43; }
    if (e4 > bv) { bv = e4; bc = s + 59; }
    if (s < 5 && e5 > bv) { bv = e5; bc = s + 75; }

    #pragma unroll
    for (int m = 8; m >= 1; m >>= 1) {
        float ov = __shfl_xor(bv, m, 64);
        int   oc = __shfl_xor(bc, m, 64);
        if (ov > bv || (ov == bv && oc < bc)) { bv = ov; bc = oc; }
    }

    const int gb = lane & 48;   // group base lane
    float bx = __shfl(e0, gb + 0, 64);
    float by = __shfl(e0, gb + 1, 64);
    float bw = __shfl(e0, gb + 2, 64);
    float bh = __shfl(e0, gb + 3, 64);
    float cf = __shfl(e0, gb + 4, 64);

    if (s == 0) {
        float score = cf * bv;
        float x  = clip01(bx / 416.0f);
        float yy = clip01(by / 416.0f);
        float w  = clip01(bw / 416.0f);
        float h  = clip01(bh / 416.0f);
        float x1 = clip01(x  - w * 0.5f);
        float y1 = clip01(yy - h * 0.5f);
        float x2 = clip01(x  + w * 0.5f);
        float y2 = clip01(yy + h * 0.5f);
        bool keep = (((x2 - x1) * (y2 - y1)) > 0.0005f) && (score > 0.5f);
        if (keep) {
            int bin = (int)((score - 0.5f) * (2.0f * (float)NBINS));
            bin = min(max(bin, 0), NBINS - 1);
            atomicAdd(&ws[WS_HIST + bin], 1u);
            unsigned int pos = atomicAdd(&ws[WS_COUNT], 1u);
            if (pos < (unsigned int)candCap)
                cand[pos] = make_uint2(__float_as_uint(score), (unsigned int)row);
        }
        if (row == 0) {
            float* r0 = (float*)&ws[WS_ROW0];
            r0[0] = score; r0[1] = (float)bc;
            r0[2] = x1; r0[3] = y1; r0[4] = x2; r0[5] = y2;
        }
    }
}

__global__ void threshold_kernel(unsigned int* __restrict__ ws)
{
    __shared__ unsigned int chunk[256];
    const int t = threadIdx.x;
    unsigned int ssum = 0;
    for (int i = 0; i < 32; i++) ssum += ws[WS_HIST + t * 32 + i];
    chunk[t] = ssum;
    __syncthreads();
    if (t == 0) {
        unsigned int total  = ws[WS_COUNT];
        unsigned int target = (total < (unsigned int)TOPK) ? total : (unsigned int)TOPK;
        unsigned int b = NBINS;   // select nothing if no candidates
        if (target > 0) {
            unsigned int cum = 0;
            int c;
            for (c = 255; c >= 0; c--) {
                if (cum + chunk[c] >= target) break;
                cum += chunk[c];
            }
            if (c < 0) {
                b = 0;
            } else {
                int bb;
                for (bb = c * 32 + 31; bb >= c * 32; bb--) {
                    cum += ws[WS_HIST + bb];
                    if (cum >= target) break;
                }
                b = (unsigned int)max(bb, c * 32);
            }
        }
        ws[WS_BSTAR] = b;
    }
}

__global__ __launch_bounds__(256) void select_kernel(
    unsigned int* __restrict__ ws, const uint2* __restrict__ cand, int candCap)
{
    unsigned int total = ws[WS_COUNT];
    if (total > (unsigned int)candCap) total = (unsigned int)candCap;
    unsigned int bstar = ws[WS_BSTAR];
    uint2* sel = (uint2*)&ws[WS_SEL];
    for (unsigned int i = blockIdx.x * 256 + threadIdx.x; i < total;
         i += gridDim.x * 256) {
        uint2 cv = cand[i];
        float score = __uint_as_float(cv.x);
        int bin = (int)((score - 0.5f) * (2.0f * (float)NBINS));
        bin = min(max(bin, 0), NBINS - 1);
        if ((unsigned int)bin >= bstar) {
            unsigned int pos = atomicAdd(&ws[WS_SELCOUNT], 1u);
            if (pos < (unsigned int)SELCAP) sel[pos] = cv;
        }
    }
}

__global__ __launch_bounds__(256) void nms_kernel(
    const float* __restrict__ y, unsigned int* __restrict__ ws,
    float* __restrict__ out)
{
    __shared__ unsigned long long keys[SELCAP];
    __shared__ float4 sboxes[SELCAP];
    __shared__ int s_picks;
    __shared__ unsigned int s_idx[10];
    __shared__ float s_score[10];
    __shared__ float4 s_box[10];
    __shared__ int s_cls[10];

    const int t = threadIdx.x;
    unsigned int M = ws[WS_SELCOUNT];
    if (M > (unsigned int)SELCAP) M = SELCAP;
    const uint2* sel = (const uint2*)&ws[WS_SEL];

    // key = score_bits<<32 | ~idx : descending sort => (score desc, idx asc)
    for (int i = t; i < SELCAP; i += 256) {
        unsigned long long k = 0ull;
        if (i < (int)M) {
            uint2 cv = sel[i];
            k = ((unsigned long long)cv.x << 32) |
                (unsigned long long)(0xFFFFFFFFu - cv.y);
        }
        keys[i] = k;
    }
    __syncthreads();

    // bitonic sort, descending
    for (int k = 2; k <= SELCAP; k <<= 1) {
        for (int j = k >> 1; j > 0; j >>= 1) {
            for (int i = t; i < SELCAP; i += 256) {
                int ixj = i ^ j;
                if (ixj > i) {
                    unsigned long long a = keys[i], b = keys[ixj];
                    bool descSeg = ((i & k) == 0);
                    if (descSeg ? (a < b) : (a > b)) { keys[i] = b; keys[ixj] = a; }
                }
            }
            __syncthreads();
        }
    }

    // decode boxes for the sorted prefix
    for (int i = t; i < (int)M; i += 256) {
        unsigned int idx = 0xFFFFFFFFu - (unsigned int)(keys[i] & 0xFFFFFFFFull);
        const float* p = y + (size_t)idx * 85;
        float x  = clip01(p[0] / 416.0f);
        float yy = clip01(p[1] / 416.0f);
        float w  = clip01(p[2] / 416.0f);
        float h  = clip01(p[3] / 416.0f);
        sboxes[i] = make_float4(clip01(x - w * 0.5f), clip01(yy - h * 0.5f),
                                clip01(x + w * 0.5f), clip01(yy + h * 0.5f));
    }
    __syncthreads();

    // sequential greedy-NMS scan (exact equivalent of the 10-step argmax loop)
    if (t == 0) {
        int np = 0;
        for (int i = 0; i < (int)M && np < 10; i++) {
            float4 b = sboxes[i];
            bool ok = true;
            for (int kk = 0; kk < np; kk++) {
                float4 r = s_box[kk];
                float ix1 = fmaxf(r.x, b.x);
                float iy1 = fmaxf(r.y, b.y);
                float ix2 = fminf(r.z, b.z);
                float iy2 = fminf(r.w, b.w);
                float inter = fmaxf(ix2 - ix1, 0.0f) * fmaxf(iy2 - iy1, 0.0f);
                float aref = (r.z - r.x) * (r.w - r.y);
                float aall = (b.z - b.x) * (b.w - b.y);
                float iou = inter / (aref + aall - inter + 1e-10f);
                if (iou > 0.45f) { ok = false; break; }
            }
            if (ok) {
                s_box[np] = b;
                s_idx[np] = 0xFFFFFFFFu - (unsigned int)(keys[i] & 0xFFFFFFFFull);
                s_score[np] = __uint_as_float((unsigned int)(keys[i] >> 32));
                np++;
            }
        }
        s_picks = np;
    }
    __syncthreads();

    // class (argmax of 80 probs) for each pick: 16 lanes per pick
    {
        int p = t >> 4, s = t & 15;
        float bv = -1.0f; int bc = 1 << 20;
        if (p < s_picks) {
            const float* pr = y + (size_t)s_idx[p] * 85 + 5;
            #pragma unroll
            for (int kk = 0; kk < 5; kk++) {
                float v = pr[s + 16 * kk];
                int c = s + 16 * kk;
                if (v > bv) { bv = v; bc = c; }
            }
        }
        #pragma unroll
        for (int m = 8; m >= 1; m >>= 1) {
            float ov = __shfl_xor(bv, m, 64);
            int   oc = __shfl_xor(bc, m, 64);
            if (ov > bv || (ov == bv && oc < bc)) { bv = ov; bc = oc; }
        }
        if (p < s_picks && s == 0) s_cls[p] = bc;
    }
    __syncthreads();

    if (t == 0) {
        const float* r0 = (const float*)&ws[WS_ROW0];
        float score0 = r0[0], class0 = r0[1];
        float4 box0 = make_float4(r0[2], r0[3], r0[4], r0[5]);
        for (int kk = 0; kk < 10; kk++) {
            bool v = kk < s_picks;
            float4 b = v ? s_box[kk] : box0;
            out[4 * kk + 0] = b.x;
            out[4 * kk + 1] = b.y;
            out[4 * kk + 2] = b.z;
            out[4 * kk + 3] = b.w;
            out[40 + kk] = v ? s_score[kk] : score0;
            out[50 + kk] = v ? (float)s_cls[kk] : class0;
            out[60 + kk] = v ? 1.0f : 0.0f;
        }
    }
}

extern "C" void kernel_launch(void* const* d_in, const int* in_sizes, int n_in,
                              void* d_out, int out_size, void* d_ws, size_t ws_size,
                              hipStream_t stream)
{
    const float* y = (const float*)d_in[0];
    unsigned int* ws = (unsigned int*)d_ws;

    long wsWords = (long)(ws_size / 4);
    long capL = (wsWords - WS_CAND) / 2;
    if (capL < 0) capL = 0;
    if (capL > ROWS) capL = ROWS;
    int candCap = (int)capL;
    uint2* cand = (uint2*)(ws + WS_CAND);

    init_kernel<<<dim3((NBINS + 255) / 256), dim3(256), 0, stream>>>(ws);
    decode_kernel<<<dim3(ROWS / 16), dim3(256), 0, stream>>>(y, ws, cand, candCap);
    threshold_kernel<<<dim3(1), dim3(256), 0, stream>>>(ws);
    select_kernel<<<dim3((ROWS + 255) / 256), dim3(256), 0, stream>>>(ws, cand, candCap);
    nms_kernel<<<dim3(1), dim3(256), 0, stream>>>(y, ws, (float*)d_out);
}

// Round 2
// 104.737 us; speedup vs baseline: 17.8053x; 17.8053x over previous
//
#include <hip/hip_runtime.h>

#define ROWS   681408        // 64 * 10647
#define NBINS  8192
#define TOPK   512
#define SELCAP 1024

// ws word offsets
#define WS_SELCOUNT 1
#define WS_BSTAR    2
#define WS_ROW0     4        // 6 floats: score, class, x1,y1,x2,y2
#define WS_HIST     16       // 8192 uints -> words 16..8207
#define WS_SEL      8448     // uint2[SELCAP] -> words 8448..10495
#define WS_SCORES   10496    // float[ROWS]

#define NEGF (-1.0e9f)

__device__ __forceinline__ float clip01(float v) {
    return fminf(fmaxf(v, 0.0f), 1.0f);
}

__global__ void init_kernel(unsigned int* __restrict__ ws) {
    int i = blockIdx.x * 256 + threadIdx.x;
    if (i < NBINS) ws[WS_HIST + i] = 0u;
    if (i < 4) ws[i] = 0u;
}

__global__ __launch_bounds__(256) void decode_kernel(
    const float* __restrict__ y, unsigned int* __restrict__ ws,
    float* __restrict__ scores)
{
    const int t    = threadIdx.x;
    const int lane = t & 63;
    const int wave = t >> 6;
    const int g    = lane >> 4;   // 16-lane group within wave
    const int s    = lane & 15;
    const int row  = blockIdx.x * 16 + wave * 4 + g;   // exact grid, no tail

    const float* p = y + (size_t)row * 85;
    float e0 = p[s];
    float e1 = p[s + 16];
    float e2 = p[s + 32];
    float e3 = p[s + 48];
    float e4 = p[s + 64];
    float e5 = (s < 5) ? p[s + 80] : -1.0f;

    // per-lane argmax over probs (elements 5..84), fold in ascending class
    // order with strict > so the FIRST index wins ties (jnp.argmax semantics)
    float bv; int bc;
    if (s >= 5) { bv = e0; bc = s - 5; } else { bv = -1.0f; bc = 1 << 20; }
    if (e1 > bv) { bv = e1; bc = s + 11; }
    if (e2 > bv) { bv = e2; bc = s + 27; }
    if (e3 > bv) { bv = e3; bc = s + 43; }
    if (e4 > bv) { bv = e4; bc = s + 59; }
    if (s < 5 && e5 > bv) { bv = e5; bc = s + 75; }

    #pragma unroll
    for (int m = 8; m >= 1; m >>= 1) {
        float ov = __shfl_xor(bv, m, 64);
        int   oc = __shfl_xor(bc, m, 64);
        if (ov > bv || (ov == bv && oc < bc)) { bv = ov; bc = oc; }
    }

    const int gb = lane & 48;   // group base lane
    float bx = __shfl(e0, gb + 0, 64);
    float by = __shfl(e0, gb + 1, 64);
    float bw = __shfl(e0, gb + 2, 64);
    float bh = __shfl(e0, gb + 3, 64);
    float cf = __shfl(e0, gb + 4, 64);

    if (s == 0) {
        float score = cf * bv;
        float x  = clip01(bx / 416.0f);
        float yy = clip01(by / 416.0f);
        float w  = clip01(bw / 416.0f);
        float h  = clip01(bh / 416.0f);
        float x1 = clip01(x  - w * 0.5f);
        float y1 = clip01(yy - h * 0.5f);
        float x2 = clip01(x  + w * 0.5f);
        float y2 = clip01(yy + h * 0.5f);
        bool keep = (((x2 - x1) * (y2 - y1)) > 0.0005f) && (score > 0.5f);
        scores[row] = keep ? score : NEGF;
        if (keep) {
            int bin = (int)((score - 0.5f) * (2.0f * (float)NBINS));
            bin = min(max(bin, 0), NBINS - 1);
            atomicAdd(&ws[WS_HIST + bin], 1u);   // fire-and-forget, scattered
        }
        if (row == 0) {
            float* r0 = (float*)&ws[WS_ROW0];
            r0[0] = score; r0[1] = (float)bc;
            r0[2] = x1; r0[3] = y1; r0[4] = x2; r0[5] = y2;
        }
    }
}

__global__ void threshold_kernel(unsigned int* __restrict__ ws)
{
    __shared__ unsigned int chunk[256];
    const int t = threadIdx.x;
    unsigned int ssum = 0;
    for (int i = 0; i < 32; i++) ssum += ws[WS_HIST + t * 32 + i];
    chunk[t] = ssum;
    __syncthreads();
    if (t == 0) {
        unsigned int total = 0;
        for (int c = 0; c < 256; c++) total += chunk[c];
        unsigned int target = (total < (unsigned int)TOPK) ? total : (unsigned int)TOPK;
        unsigned int b = NBINS;   // select nothing if no candidates
        if (target > 0) {
            unsigned int cum = 0;
            int c;
            for (c = 255; c >= 0; c--) {
                if (cum + chunk[c] >= target) break;
                cum += chunk[c];
            }
            if (c < 0) {
                b = 0;
            } else {
                int bb;
                for (bb = c * 32 + 31; bb >= c * 32; bb--) {
                    cum += ws[WS_HIST + bb];
                    if (cum >= target) break;
                }
                b = (unsigned int)max(bb, c * 32);
            }
        }
        ws[WS_BSTAR] = b;
    }
}

__global__ __launch_bounds__(256) void select_kernel(
    unsigned int* __restrict__ ws, const float* __restrict__ scores)
{
    unsigned int bstar = ws[WS_BSTAR];
    uint2* sel = (uint2*)&ws[WS_SEL];
    for (unsigned int i = blockIdx.x * 256 + threadIdx.x; i < (unsigned int)ROWS;
         i += gridDim.x * 256) {
        float sc = scores[i];
        if (sc > 0.5f) {                      // all keepers have score > 0.5
            int bin = (int)((sc - 0.5f) * (2.0f * (float)NBINS));
            bin = min(max(bin, 0), NBINS - 1);
            if ((unsigned int)bin >= bstar) {
                unsigned int pos = atomicAdd(&ws[WS_SELCOUNT], 1u);
                if (pos < (unsigned int)SELCAP)
                    sel[pos] = make_uint2(__float_as_uint(sc), i);
            }
        }
    }
}

__global__ __launch_bounds__(256) void nms_kernel(
    const float* __restrict__ y, unsigned int* __restrict__ ws,
    float* __restrict__ out)
{
    __shared__ unsigned long long keys[SELCAP];
    __shared__ float4 sboxes[SELCAP];
    __shared__ int s_picks;
    __shared__ unsigned int s_idx[10];
    __shared__ float s_score[10];
    __shared__ float4 s_box[10];
    __shared__ int s_cls[10];

    const int t = threadIdx.x;
    unsigned int M = ws[WS_SELCOUNT];
    if (M > (unsigned int)SELCAP) M = SELCAP;
    const uint2* sel = (const uint2*)&ws[WS_SEL];

    // key = score_bits<<32 | ~idx : descending sort => (score desc, idx asc)
    for (int i = t; i < SELCAP; i += 256) {
        unsigned long long k = 0ull;
        if (i < (int)M) {
            uint2 cv = sel[i];
            k = ((unsigned long long)cv.x << 32) |
                (unsigned long long)(0xFFFFFFFFu - cv.y);
        }
        keys[i] = k;
    }
    __syncthreads();

    // bitonic sort, descending
    for (int k = 2; k <= SELCAP; k <<= 1) {
        for (int j = k >> 1; j > 0; j >>= 1) {
            for (int i = t; i < SELCAP; i += 256) {
                int ixj = i ^ j;
                if (ixj > i) {
                    unsigned long long a = keys[i], b = keys[ixj];
                    bool descSeg = ((i & k) == 0);
                    if (descSeg ? (a < b) : (a > b)) { keys[i] = b; keys[ixj] = a; }
                }
            }
            __syncthreads();
        }
    }

    // decode boxes for the sorted prefix
    for (int i = t; i < (int)M; i += 256) {
        unsigned int idx = 0xFFFFFFFFu - (unsigned int)(keys[i] & 0xFFFFFFFFull);
        const float* p = y + (size_t)idx * 85;
        float x  = clip01(p[0] / 416.0f);
        float yy = clip01(p[1] / 416.0f);
        float w  = clip01(p[2] / 416.0f);
        float h  = clip01(p[3] / 416.0f);
        sboxes[i] = make_float4(clip01(x - w * 0.5f), clip01(yy - h * 0.5f),
                                clip01(x + w * 0.5f), clip01(yy + h * 0.5f));
    }
    __syncthreads();

    // sequential greedy-NMS scan (exact equivalent of the 10-step argmax loop)
    if (t == 0) {
        int np = 0;
        for (int i = 0; i < (int)M && np < 10; i++) {
            float4 b = sboxes[i];
            bool ok = true;
            for (int kk = 0; kk < np; kk++) {
                float4 r = s_box[kk];
                float ix1 = fmaxf(r.x, b.x);
                float iy1 = fmaxf(r.y, b.y);
                float ix2 = fminf(r.z, b.z);
                float iy2 = fminf(r.w, b.w);
                float inter = fmaxf(ix2 - ix1, 0.0f) * fmaxf(iy2 - iy1, 0.0f);
                float aref = (r.z - r.x) * (r.w - r.y);
                float aall = (b.z - b.x) * (b.w - b.y);
                float iou = inter / (aref + aall - inter + 1e-10f);
                if (iou > 0.45f) { ok = false; break; }
            }
            if (ok) {
                s_box[np] = b;
                s_idx[np] = 0xFFFFFFFFu - (unsigned int)(keys[i] & 0xFFFFFFFFull);
                s_score[np] = __uint_as_float((unsigned int)(keys[i] >> 32));
                np++;
            }
        }
        s_picks = np;
    }
    __syncthreads();

    // class (argmax of 80 probs) for each pick: 16 lanes per pick
    {
        int p = t >> 4, s = t & 15;
        float bv = -1.0f; int bc = 1 << 20;
        if (p < s_picks) {
            const float* pr = y + (size_t)s_idx[p] * 85 + 5;
            #pragma unroll
            for (int kk = 0; kk < 5; kk++) {
                float v = pr[s + 16 * kk];
                int c = s + 16 * kk;
                if (v > bv) { bv = v; bc = c; }
            }
        }
        #pragma unroll
        for (int m = 8; m >= 1; m >>= 1) {
            float ov = __shfl_xor(bv, m, 64);
            int   oc = __shfl_xor(bc, m, 64);
            if (ov > bv || (ov == bv && oc < bc)) { bv = ov; bc = oc; }
        }
        if (p < s_picks && s == 0) s_cls[p] = bc;
    }
    __syncthreads();

    if (t == 0) {
        const float* r0 = (const float*)&ws[WS_ROW0];
        float score0 = r0[0], class0 = r0[1];
        float4 box0 = make_float4(r0[2], r0[3], r0[4], r0[5]);
        for (int kk = 0; kk < 10; kk++) {
            bool v = kk < s_picks;
            float4 b = v ? s_box[kk] : box0;
            out[4 * kk + 0] = b.x;
            out[4 * kk + 1] = b.y;
            out[4 * kk + 2] = b.z;
            out[4 * kk + 3] = b.w;
            out[40 + kk] = v ? s_score[kk] : score0;
            out[50 + kk] = v ? (float)s_cls[kk] : class0;
            out[60 + kk] = v ? 1.0f : 0.0f;
        }
    }
}

extern "C" void kernel_launch(void* const* d_in, const int* in_sizes, int n_in,
                              void* d_out, int out_size, void* d_ws, size_t ws_size,
                              hipStream_t stream)
{
    const float* y = (const float*)d_in[0];
    unsigned int* ws = (unsigned int*)d_ws;
    float* scores = (float*)(ws + WS_SCORES);

    init_kernel<<<dim3((NBINS + 255) / 256), dim3(256), 0, stream>>>(ws);
    decode_kernel<<<dim3(ROWS / 16), dim3(256), 0, stream>>>(y, ws, scores);
    threshold_kernel<<<dim3(1), dim3(256), 0, stream>>>(ws);
    select_kernel<<<dim3(2048), dim3(256), 0, stream>>>(ws, scores);
    nms_kernel<<<dim3(1), dim3(256), 0, stream>>>(y, ws, (float*)d_out);
}

// Round 3
// 77.746 us; speedup vs baseline: 23.9868x; 1.3472x over previous
//
#include <hip/hip_runtime.h>

#define ROWS   681408        // 64 * 10647
#define NBINS  8192
#define CAP    64            // bucket capacity per bin
#define TOPK   192
#define SELCAP 256

// ws word offsets
#define WS_ROW0     4        // 6 floats: score, class, x1,y1,x2,y2
#define WS_CNT      16       // 8192 uints -> words 16..8207
#define WS_BUCKET   8448     // uint2[NBINS*CAP] -> 1,048,576 words (4 MB)

__device__ __forceinline__ float clip01(float v) {
    return fminf(fmaxf(v, 0.0f), 1.0f);
}

__global__ void init_kernel(unsigned int* __restrict__ ws) {
    int i = blockIdx.x * 256 + threadIdx.x;
    if (i < NBINS) ws[WS_CNT + i] = 0u;
}

__global__ __launch_bounds__(256) void decode_kernel(
    const float* __restrict__ y, unsigned int* __restrict__ ws)
{
    const int t    = threadIdx.x;
    const int lane = t & 63;
    const int wave = t >> 6;
    const int g    = lane >> 4;   // 16-lane group within wave
    const int s    = lane & 15;
    const int row  = blockIdx.x * 16 + wave * 4 + g;   // exact grid, no tail

    const float* p = y + (size_t)row * 85;
    float e0 = p[s];
    float e1 = p[s + 16];
    float e2 = p[s + 32];
    float e3 = p[s + 48];
    float e4 = p[s + 64];
    float e5 = (s < 5) ? p[s + 80] : -1.0f;

    // per-lane argmax over probs (elements 5..84), fold in ascending class
    // order with strict > so the FIRST index wins ties (jnp.argmax semantics)
    float bv; int bc;
    if (s >= 5) { bv = e0; bc = s - 5; } else { bv = -1.0f; bc = 1 << 20; }
    if (e1 > bv) { bv = e1; bc = s + 11; }
    if (e2 > bv) { bv = e2; bc = s + 27; }
    if (e3 > bv) { bv = e3; bc = s + 43; }
    if (e4 > bv) { bv = e4; bc = s + 59; }
    if (s < 5 && e5 > bv) { bv = e5; bc = s + 75; }

    #pragma unroll
    for (int m = 8; m >= 1; m >>= 1) {
        float ov = __shfl_xor(bv, m, 64);
        int   oc = __shfl_xor(bc, m, 64);
        if (ov > bv || (ov == bv && oc < bc)) { bv = ov; bc = oc; }
    }

    const int gb = lane & 48;   // group base lane
    float bx = __shfl(e0, gb + 0, 64);
    float by = __shfl(e0, gb + 1, 64);
    float bw = __shfl(e0, gb + 2, 64);
    float bh = __shfl(e0, gb + 3, 64);
    float cf = __shfl(e0, gb + 4, 64);

    if (s == 0) {
        float score = cf * bv;
        float x  = clip01(bx / 416.0f);
        float yy = clip01(by / 416.0f);
        float w  = clip01(bw / 416.0f);
        float h  = clip01(bh / 416.0f);
        float x1 = clip01(x  - w * 0.5f);
        float y1 = clip01(yy - h * 0.5f);
        float x2 = clip01(x  + w * 0.5f);
        float y2 = clip01(yy + h * 0.5f);
        bool keep = (((x2 - x1) * (y2 - y1)) > 0.0005f) && (score > 0.5f);
        if (keep) {
            int bin = (int)((score - 0.5f) * (2.0f * (float)NBINS));
            bin = min(max(bin, 0), NBINS - 1);
            unsigned int pos = atomicAdd(&ws[WS_CNT + bin], 1u);
            if (pos < (unsigned int)CAP) {
                uint2* bucket = (uint2*)&ws[WS_BUCKET];
                bucket[bin * CAP + pos] =
                    make_uint2(__float_as_uint(score), (unsigned int)row);
            }
        }
        if (row == 0) {
            float* r0 = (float*)&ws[WS_ROW0];
            r0[0] = score; r0[1] = (float)bc;
            r0[2] = x1; r0[3] = y1; r0[4] = x2; r0[5] = y2;
        }
    }
}

__global__ __launch_bounds__(256) void nms_kernel(
    const float* __restrict__ y, unsigned int* __restrict__ ws,
    float* __restrict__ out)
{
    __shared__ unsigned int chunk[256];
    __shared__ unsigned long long keys[SELCAP];
    __shared__ float4 sboxes[SELCAP];
    __shared__ int s_bstar;
    __shared__ unsigned int s_m;
    __shared__ int s_picks;
    __shared__ unsigned int s_idx[10];
    __shared__ float s_score[10];
    __shared__ float4 s_box[10];
    __shared__ int s_cls[10];

    const int t = threadIdx.x;
    const uint2* bucket = (const uint2*)&ws[WS_BUCKET];

    // ---- threshold: find bin b* so that count(bins >= b*) >= min(TOPK, total)
    unsigned int ssum = 0;
    for (int i = 0; i < 32; i++) {
        unsigned int c = ws[WS_CNT + t * 32 + i];
        ssum += (c < (unsigned int)CAP) ? c : (unsigned int)CAP;
    }
    chunk[t] = ssum;
    // pre-zero sort keys while we're here
    for (int i = t; i < SELCAP; i += 256) keys[i] = 0ull;
    __syncthreads();
    if (t == 0) {
        unsigned int total = 0;
        for (int c = 0; c < 256; c++) total += chunk[c];
        unsigned int target = (total < (unsigned int)TOPK) ? total : (unsigned int)TOPK;
        int b = NBINS;   // select nothing if no candidates
        if (target > 0) {
            unsigned int cum = 0;
            int c;
            for (c = 255; c >= 0; c--) {
                if (cum + chunk[c] >= target) break;
                cum += chunk[c];
            }
            if (c < 0) {
                b = 0;
            } else {
                int bb;
                for (bb = c * 32 + 31; bb >= c * 32; bb--) {
                    unsigned int cc = ws[WS_CNT + bb];
                    cum += (cc < (unsigned int)CAP) ? cc : (unsigned int)CAP;
                    if (cum >= target) break;
                }
                b = max(bb, c * 32);
            }
        }
        s_bstar = b;
        s_m = 0u;
    }
    __syncthreads();

    // ---- gather all entries from bins >= b* (order fixed by the sort below)
    for (int bin = s_bstar + t; bin < NBINS; bin += 256) {
        unsigned int c = ws[WS_CNT + bin];
        if (c > (unsigned int)CAP) c = CAP;
        for (unsigned int j = 0; j < c; j++) {
            uint2 cv = bucket[bin * CAP + j];
            unsigned int pos = atomicAdd(&s_m, 1u);
            if (pos < (unsigned int)SELCAP)
                keys[pos] = ((unsigned long long)cv.x << 32) |
                            (unsigned long long)(0xFFFFFFFFu - cv.y);
        }
    }
    __syncthreads();
    unsigned int M = s_m;
    if (M > (unsigned int)SELCAP) M = SELCAP;

    // ---- bitonic sort, descending: (score desc, idx asc)
    for (int k = 2; k <= SELCAP; k <<= 1) {
        for (int j = k >> 1; j > 0; j >>= 1) {
            for (int i = t; i < SELCAP; i += 256) {
                int ixj = i ^ j;
                if (ixj > i) {
                    unsigned long long a = keys[i], b = keys[ixj];
                    bool descSeg = ((i & k) == 0);
                    if (descSeg ? (a < b) : (a > b)) { keys[i] = b; keys[ixj] = a; }
                }
            }
            __syncthreads();
        }
    }

    // ---- decode boxes for the sorted prefix
    for (int i = t; i < (int)M; i += 256) {
        unsigned int idx = 0xFFFFFFFFu - (unsigned int)(keys[i] & 0xFFFFFFFFull);
        const float* p = y + (size_t)idx * 85;
        float x  = clip01(p[0] / 416.0f);
        float yy = clip01(p[1] / 416.0f);
        float w  = clip01(p[2] / 416.0f);
        float h  = clip01(p[3] / 416.0f);
        sboxes[i] = make_float4(clip01(x - w * 0.5f), clip01(yy - h * 0.5f),
                                clip01(x + w * 0.5f), clip01(yy + h * 0.5f));
    }
    __syncthreads();

    // ---- sequential greedy-NMS scan (exact equivalent of the 10-step argmax loop)
    if (t == 0) {
        int np = 0;
        for (int i = 0; i < (int)M && np < 10; i++) {
            float4 b = sboxes[i];
            bool ok = true;
            for (int kk = 0; kk < np; kk++) {
                float4 r = s_box[kk];
                float ix1 = fmaxf(r.x, b.x);
                float iy1 = fmaxf(r.y, b.y);
                float ix2 = fminf(r.z, b.z);
                float iy2 = fminf(r.w, b.w);
                float inter = fmaxf(ix2 - ix1, 0.0f) * fmaxf(iy2 - iy1, 0.0f);
                float aref = (r.z - r.x) * (r.w - r.y);
                float aall = (b.z - b.x) * (b.w - b.y);
                float iou = inter / (aref + aall - inter + 1e-10f);
                if (iou > 0.45f) { ok = false; break; }
            }
            if (ok) {
                s_box[np] = b;
                s_idx[np] = 0xFFFFFFFFu - (unsigned int)(keys[i] & 0xFFFFFFFFull);
                s_score[np] = __uint_as_float((unsigned int)(keys[i] >> 32));
                np++;
            }
        }
        s_picks = np;
    }
    __syncthreads();

    // ---- class (argmax of 80 probs) for each pick: 16 lanes per pick
    {
        int p = t >> 4, s = t & 15;
        float bv = -1.0f; int bc = 1 << 20;
        if (p < s_picks) {
            const float* pr = y + (size_t)s_idx[p] * 85 + 5;
            #pragma unroll
            for (int kk = 0; kk < 5; kk++) {
                float v = pr[s + 16 * kk];
                int c = s + 16 * kk;
                if (v > bv) { bv = v; bc = c; }
            }
        }
        #pragma unroll
        for (int m = 8; m >= 1; m >>= 1) {
            float ov = __shfl_xor(bv, m, 64);
            int   oc = __shfl_xor(bc, m, 64);
            if (ov > bv || (ov == bv && oc < bc)) { bv = ov; bc = oc; }
        }
        if (p < s_picks && s == 0) s_cls[p] = bc;
    }
    __syncthreads();

    if (t == 0) {
        const float* r0 = (const float*)&ws[WS_ROW0];
        float score0 = r0[0], class0 = r0[1];
        float4 box0 = make_float4(r0[2], r0[3], r0[4], r0[5]);
        for (int kk = 0; kk < 10; kk++) {
            bool v = kk < s_picks;
            float4 b = v ? s_box[kk] : box0;
            out[4 * kk + 0] = b.x;
            out[4 * kk + 1] = b.y;
            out[4 * kk + 2] = b.z;
            out[4 * kk + 3] = b.w;
            out[40 + kk] = v ? s_score[kk] : score0;
            out[50 + kk] = v ? (float)s_cls[kk] : class0;
            out[60 + kk] = v ? 1.0f : 0.0f;
        }
    }
}

extern "C" void kernel_launch(void* const* d_in, const int* in_sizes, int n_in,
                              void* d_out, int out_size, void* d_ws, size_t ws_size,
                              hipStream_t stream)
{
    const float* y = (const float*)d_in[0];
    unsigned int* ws = (unsigned int*)d_ws;

    init_kernel<<<dim3(NBINS / 256), dim3(256), 0, stream>>>(ws);
    decode_kernel<<<dim3(ROWS / 16), dim3(256), 0, stream>>>(y, ws);
    nms_kernel<<<dim3(1), dim3(256), 0, stream>>>(y, ws, (float*)d_out);
}